// Round 13
// baseline (126.556 us; speedup 1.0000x reference)
//
#include <hip/hip_runtime.h>
#include <math.h>

#define NQ 12
#define DIM 4096
#define NL 6
#define TPB 256

// ---------------------------------------------------------------------------
// R20: persistent blocks — grid 1024, each block runs TWO elements (2b,
// 2b+1) sequentially through the verified R15/R19 pipeline, reusing the one
// 32 KB buffer.
//
// R19 observation: OccupancyPercent is ~35-36% in EVERY variant of this
// structure regardless of the LDS cap (R8: cap 4 blocks/CU -> 34.6%; R15/19:
// cap 5 -> 35.5/36.6%). Measured residency ~2.8 blocks/CU vs cap 5: with
// 2048 blocks each living only ~30us, the dispatch spends much of its life
// in scheduler ramp/drain/backfill. Persistent blocks (1024 = 4/CU exactly,
// all resident from t~0, 2x lifetime) should hold residency at the cap.
//
// Per-element body is byte-identical to R19 (verified: passed, absmax
// 0.0039, bench 125us). New code: outer it=0,1 loop + one defensive barrier
// between elements (buffer-reuse analysis says same-lane program order
// already protects st[0..7]; barrier is insurance per R18's lesson).
// Pre-committed null branch: bench ~125 +-3 -> occupancy counter is an
// artifact, structure has converged at R19.
// ---------------------------------------------------------------------------

// ---- d_ws table layout (float offsets) ----
#define WS_WA0 0      // 256 f2  : layer-0 D_phi thread factor e^{i fA0(t)}
#define WS_W   512    // 5*256 f2: merged D_om(l)*D_phi(l+1) thread factor
#define WS_ZA0 3072   // 16 f2   : layer-0 D_phi group factor (label bits 0-3)
#define WS_ZM  3104   // 5*2*16 f2: merged group factor, idx ((l*2+t7)*16+j)
#define WS_RYT 3424   // 72 float4: (w,w,s,s) per (l,wire)  [lifting coeffs]
#define WS_FLOATS 3712  // 14848 bytes total

typedef float f2 __attribute__((ext_vector_type(2)));

__device__ __forceinline__ f2 pk_mul(f2 a, f2 b) {
  f2 d; asm("v_pk_mul_f32 %0, %1, %2" : "=v"(d) : "v"(a), "v"(b)); return d;
}
__device__ __forceinline__ f2 pk_fma(f2 a, f2 b, f2 c) {
  f2 d; asm("v_pk_fma_f32 %0, %1, %2, %3" : "=v"(d) : "v"(a), "v"(b), "v"(c)); return d;
}
// complex mul, both operands packed (re,im)
__device__ __forceinline__ f2 cmulp(f2 a, f2 c) {
  f2 r1, d;
  asm("v_pk_mul_f32 %0, %1, %2 op_sel:[0,0] op_sel_hi:[0,1]"
      : "=v"(r1) : "v"(a), "v"(c));
  asm("v_pk_fma_f32 %0, %1, %2, %3 op_sel:[1,1,0] op_sel_hi:[1,0,1] neg_lo:[1,0,0]"
      : "=v"(d) : "v"(a), "v"(c), "v"(r1));
  return d;
}

// Lifting RY pair update: a += w*b; b += s*a; a += w*b
// == a' = c*a - s*b ; b' = s*a + c*b   (3 pk-FMA vs 4; R15-verified)
template<int BIT>
__device__ __forceinline__ void apply_ry16(f2 v[16], f2 ww, f2 ss) {
  #pragma unroll
  for (int j = 0; j < 16; ++j) {
    if (j & (1 << BIT)) continue;
    const int k = j | (1 << BIT);
    f2 a = v[j], b = v[k];
    a = pk_fma(b, ww, a);
    b = pk_fma(a, ss, b);
    a = pk_fma(b, ww, a);
    v[j] = a; v[k] = b;
  }
}

// ---------------------------------------------------------------------------
// Prep kernel — verbatim R15/R19 (verified).
// w layout: w[(l*NQ + q)*3 + c], c: 0=phi, 1=theta, 2=omega.
// ---------------------------------------------------------------------------
__global__ __launch_bounds__(256)
void qprep_kernel(const float* __restrict__ w, float* __restrict__ ws) {
  const int t = threadIdx.x;

  {
    float f = 0.f;
    #pragma unroll
    for (int k = 0; k < 8; ++k) {
      float p = w[(0*NQ + 7 - k)*3 + 0];
      f += ((t >> k) & 1) ? 0.5f*p : -0.5f*p;
    }
    float sv, cv; sincosf(f, &sv, &cv);
    ws[WS_WA0 + 2*t] = cv; ws[WS_WA0 + 2*t + 1] = sv;
  }

  #pragma unroll 1
  for (int l = 0; l < NL-1; ++l) {
    float f = 0.f;
    const int gt = t ^ (t >> 1);
    #pragma unroll
    for (int k = 0; k < 8; ++k) {
      float om = w[(l*NQ + 11 - k)*3 + 2];
      f += ((t >> k) & 1) ? 0.5f*om : -0.5f*om;
    }
    #pragma unroll
    for (int k = 0; k < 7; ++k) {
      float ph = w[((l+1)*NQ + 11 - k)*3 + 0];
      f += ((gt >> k) & 1) ? 0.5f*ph : -0.5f*ph;
    }
    float sv, cv; sincosf(f, &sv, &cv);
    ws[WS_W + (l*256 + t)*2] = cv; ws[WS_W + (l*256 + t)*2 + 1] = sv;
  }

  if (t < 16) {
    float f = 0.f;
    #pragma unroll
    for (int m = 0; m < 4; ++m) {
      float p = w[(0*NQ + 11 - m)*3 + 0];
      f += ((t >> m) & 1) ? 0.5f*p : -0.5f*p;
    }
    float sv, cv; sincosf(f, &sv, &cv);
    ws[WS_ZA0 + 2*t] = cv; ws[WS_ZA0 + 2*t + 1] = sv;
  }

  if (t < 160) {
    const int l = t >> 5, h = (t >> 4) & 1, j = t & 15;
    float f = 0.f;
    #pragma unroll
    for (int m = 0; m < 4; ++m) {
      float om = w[(l*NQ + 3 - m)*3 + 2];
      f += ((j >> m) & 1) ? 0.5f*om : -0.5f*om;
    }
    {
      float p4 = w[((l+1)*NQ + 4)*3 + 0];
      f += (h ^ (j & 1)) ? 0.5f*p4 : -0.5f*p4;
    }
    const int gj = j ^ (j >> 1);
    #pragma unroll
    for (int m = 0; m < 4; ++m) {
      float ph = w[((l+1)*NQ + 3 - m)*3 + 0];
      f += ((gj >> m) & 1) ? 0.5f*ph : -0.5f*ph;
    }
    float sv, cv; sincosf(f, &sv, &cv);
    ws[WS_ZM + 2*t] = cv; ws[WS_ZM + 2*t + 1] = sv;
  }

  // lifting coeffs of the half-angle rotation: s = sin(th/2), w = -tan(th/4)
  if (t < NL*NQ) {
    float th = w[t*3 + 1];
    float sv = sinf(0.5f*th);
    float wv = -tanf(0.25f*th);
    ((float4*)(ws + WS_RYT))[t] = make_float4(wv, wv, sv, sv);
  }
}

// ---------------------------------------------------------------------------
// Main kernel: persistent blocks, 2 elements sequentially per block.
// LDS = 32768 B (one state buffer, reused across elements).
// ---------------------------------------------------------------------------
__global__ __launch_bounds__(TPB, 1)
void qsim12_kernel(const float* __restrict__ x, const float* __restrict__ ws,
                   float* __restrict__ out) {
  __shared__ __align__(16) float st[2*DIM];   // 32 KB state (swizzled) ONLY

  const int t = threadIdx.x;
  char* stb = (char*)st;

  // Precomputed byte-address bases (verified R5/R7 — element-independent).
  int baseA[8], baseB[8];
  #pragma unroll
  for (int m = 0; m < 8; ++m) {
    baseA[m] = (t << 7) + (((2*m) ^ (t & 14)) << 3);                 // phys14, A b128
    baseB[m] = ((t >> 4) << 11) + ((((t & 15) ^ (2*m))) << 3);       // + j*128
  }
  const int baseC = ((t >> 4) << 7) + ((((t & 15) ^ ((t >> 4) & 15))) << 3);  // + j*2048
  const int G = t ^ (t >> 1);
  int baseS[2];
  #pragma unroll
  for (int par = 0; par < 2; ++par) {
    const int k8 = par << 3;
    baseS[par] = ((((G >> 4) & 15) ^ k8) << 7)
               + ((((G & 15) ^ ((G >> 4) & 14) ^ k8)) << 3);
  }

  #define RY(BIT, WQ)                                                     \
    { const float4 r = *(const float4*)(ws + WS_RYT + 4*(l*NQ + (WQ)));   \
      apply_ry16<BIT>(v, (f2){r.x, r.y}, (f2){r.z, r.w}); }

  #pragma unroll 1
  for (int it = 0; it < 2; ++it) {
    const int e = blockIdx.x*2 + it;
    if (it) __syncthreads();   // insurance: prior element fully drained

    // x cos/sin: lanes 0-11 of each wave compute, readlane-broadcast.
    float csx[NQ], csy[NQ];
    {
      const int q = t & 63;
      float xv = (q < NQ) ? x[e*NQ + q] : 0.f;
      float sv, cv; sincosf(0.5f*xv, &sv, &cv);
      #pragma unroll
      for (int qq = 0; qq < NQ; ++qq) {
        csx[qq] = __int_as_float(__builtin_amdgcn_readlane(__float_as_int(cv), qq));
        csy[qq] = __int_as_float(__builtin_amdgcn_readlane(__float_as_int(sv), qq));
      }
    }

    f2 v[16];

    // ---- Init: amp(label) = prod_w (bit? sin:cos) * (-i)^popcount(label).
    {
      float rhi = 1.f;
      #pragma unroll
      for (int k = 0; k < 8; ++k)
        rhi *= ((t >> k) & 1) ? csy[7-k] : csx[7-k];
      const int popt = __popc(t);
      #pragma unroll
      for (int j = 0; j < 16; ++j) {
        float r = rhi;
        #pragma unroll
        for (int m = 0; m < 4; ++m)
          r *= ((j >> m) & 1) ? csy[11-m] : csx[11-m];
        const int pj = (popt + __popc(j)) & 3;
        if      (pj == 0) v[j] = (f2){ r, 0.f};
        else if (pj == 1) v[j] = (f2){0.f, -r};
        else if (pj == 2) v[j] = (f2){-r, 0.f};
        else              v[j] = (f2){0.f,  r};
      }
    }

    #pragma unroll 1
    for (int l = 0; l < NL; ++l) {
      // ---- pass A: wires 11..8 (label bits 0..3)
      if (l > 0) {
        // diag for this boundary was applied (merged) at pass C of l-1
        #pragma unroll
        for (int m = 0; m < 8; ++m) {
          float4 q4 = *(const float4*)(stb + baseA[m]);
          v[2*m]   = (f2){q4.x, q4.y};
          v[2*m+1] = (f2){q4.z, q4.w};
        }
      } else {
        // D_phi(0): group (label bits 0-3) table x thread factor
        const float2 wv = *(const float2*)(ws + WS_WA0 + 2*t);
        const f2 wA0 = (f2){wv.x, wv.y};
        #pragma unroll
        for (int j = 0; j < 16; ++j) {
          const float2 zv = *(const float2*)(ws + WS_ZA0 + 2*j);
          v[j] = cmulp(cmulp(v[j], (f2){zv.x, zv.y}), wA0);
        }
      }
      RY(0,11) RY(1,10) RY(2,9) RY(3,8)
      #pragma unroll
      for (int m = 0; m < 8; ++m)
        *(float4*)(stb + baseA[m]) =
            make_float4(v[2*m].x, v[2*m].y, v[2*m+1].x, v[2*m+1].y);
      __syncthreads();

      // ---- pass B: wires 7..4 (label bits 4..7); load phys14, store phys15
      #pragma unroll
      for (int m = 0; m < 8; ++m) {
        v[2*m]   = *(const f2*)(stb + baseB[m] + (2*m)*128);
        v[2*m+1] = *(const f2*)(stb + baseB[m] + (2*m+1)*128);
      }
      RY(0,7) RY(1,6) RY(2,5) RY(3,4)
      #pragma unroll
      for (int m = 0; m < 8; ++m) {
        *(f2*)(stb + baseB[m] + (2*m)*128)         = v[2*m];
        *(f2*)(stb + (baseB[m] ^ 8) + (2*m+1)*128) = v[2*m+1];
      }
      __syncthreads();

      // ---- pass C: wires 3..0 (label bits 8..11); load phys15
      #pragma unroll
      for (int j = 0; j < 16; ++j)
        v[j] = *(const f2*)(stb + baseC + j*2048);
      RY(0,3) RY(1,2) RY(2,1) RY(3,0)
      if (l < NL-1) {
        // merged diag: D_om(l)*D_phi(l+1) at post-CNOT label gray(lambda).
        const float2 wv = *(const float2*)(ws + WS_W + (l*TPB + t)*2);
        const f2 W = (f2){wv.x, wv.y};
        const float* zmb = ws + WS_ZM + ((l*2 + ((t >> 7) & 1))*16)*2;
        #pragma unroll
        for (int j = 0; j < 16; ++j) {
          const float2 zv = *(const float2*)(zmb + 2*j);
          v[j] = cmulp(cmulp(v[j], (f2){zv.x, zv.y}), W);
        }
        // store with CNOT fold: slot = gray(label), layout phys14
        #pragma unroll
        for (int j = 0; j < 16; ++j) {
          const int g4 = (j ^ (j >> 1)) & 15;
          *(f2*)(stb + baseS[j & 1] + (g4 << 11)) = v[j];
        }
        __syncthreads();
      }
    }

    // ---- Epilogue: post-CNOT wire0 = j3, wire1 = j2^j3.
    float a0 = 0.f, a1 = 0.f;
    #pragma unroll
    for (int j = 0; j < 16; ++j) {
      float pr = v[j].x*v[j].x + v[j].y*v[j].y;
      a0 += ((j >> 3) & 1) ? -pr : pr;
      a1 += (((j >> 2) ^ (j >> 3)) & 1) ? -pr : pr;
    }
    #pragma unroll
    for (int off = 32; off >= 1; off >>= 1) {
      a0 += __shfl_down(a0, off);
      a1 += __shfl_down(a1, off);
    }
    __syncthreads();                 // all LDS reads done before st reuse
    if ((t & 63) == 0) { st[(t >> 6)*2] = a0; st[(t >> 6)*2 + 1] = a1; }
    __syncthreads();
    if (t == 0) {
      out[e*2 + 0] = st[0] + st[2] + st[4] + st[6];
      out[e*2 + 1] = st[1] + st[3] + st[5] + st[7];
    }
  }
}

extern "C" void kernel_launch(void* const* d_in, const int* in_sizes, int n_in,
                              void* d_out, int out_size, void* d_ws, size_t ws_size,
                              hipStream_t stream) {
  const float* x = (const float*)d_in[0];      // (B, 12) f32
  const float* w = (const float*)d_in[1];      // (6, 12, 3) f32
  float* out = (float*)d_out;                  // (B, 2) f32
  float* ws = (float*)d_ws;                    // needs >= 14848 B
  int B = in_sizes[0] / NQ;                    // B = 2048 (even)
  qprep_kernel<<<1, 256, 0, stream>>>(w, ws);
  qsim12_kernel<<<B/2, TPB, 0, stream>>>(x, ws, out);
}

// Round 15
// 126.330 us; speedup vs baseline: 1.0018x; 1.0018x over previous
//
#include <hip/hip_runtime.h>
#include <math.h>

#define NQ 12
#define DIM 4096
#define NL 6
#define TPB 256

// ---------------------------------------------------------------------------
// R21 (resubmit — round 14 failed on container acquisition, kernel never
// ran): R19 (verified best: passed x3, absmax 0.0039, bench 125us) +
// s_setprio(1) around register-only compute clusters (T5).
//
// R20 post-mortem: persistent blocks = null (bench 126.6 vs 125.4, occupancy
// unchanged 33%) -> occupancy counter is a time-average artifact; the stall
// is intrinsic phase serialization (VALU -> DS -> barrier per pass), with
// floors VALU ~32us / LDS-BW ~31us vs 80us measured. Occupancy levers
// closed. Remaining cheap lever: priority arbitration ACROSS staggered
// blocks on a CU (~3 blocks at different phases): raise prio while in
// register-only RY/diag clusters, drop before LDS store + barrier. Prior
// mixed (m190 GEMM-null lockstep; m191 attn +4-7% staggered) -> genuine A/B.
// Pre-committed: bench in [122,129] = null -> family converged at R19.
//
// Body byte-identical to R19 except the 6 setprio pairs per layer.
// ---------------------------------------------------------------------------

// ---- d_ws table layout (float offsets) ----
#define WS_WA0 0      // 256 f2  : layer-0 D_phi thread factor e^{i fA0(t)}
#define WS_W   512    // 5*256 f2: merged D_om(l)*D_phi(l+1) thread factor
#define WS_ZA0 3072   // 16 f2   : layer-0 D_phi group factor (label bits 0-3)
#define WS_ZM  3104   // 5*2*16 f2: merged group factor, idx ((l*2+t7)*16+j)
#define WS_RYT 3424   // 72 float4: (w,w,s,s) per (l,wire)  [lifting coeffs]
#define WS_FLOATS 3712  // 14848 bytes total

typedef float f2 __attribute__((ext_vector_type(2)));

__device__ __forceinline__ f2 pk_mul(f2 a, f2 b) {
  f2 d; asm("v_pk_mul_f32 %0, %1, %2" : "=v"(d) : "v"(a), "v"(b)); return d;
}
__device__ __forceinline__ f2 pk_fma(f2 a, f2 b, f2 c) {
  f2 d; asm("v_pk_fma_f32 %0, %1, %2, %3" : "=v"(d) : "v"(a), "v"(b), "v"(c)); return d;
}
// complex mul, both operands packed (re,im)
__device__ __forceinline__ f2 cmulp(f2 a, f2 c) {
  f2 r1, d;
  asm("v_pk_mul_f32 %0, %1, %2 op_sel:[0,0] op_sel_hi:[0,1]"
      : "=v"(r1) : "v"(a), "v"(c));
  asm("v_pk_fma_f32 %0, %1, %2, %3 op_sel:[1,1,0] op_sel_hi:[1,0,1] neg_lo:[1,0,0]"
      : "=v"(d) : "v"(a), "v"(c), "v"(r1));
  return d;
}

// Lifting RY pair update: a += w*b; b += s*a; a += w*b
// == a' = c*a - s*b ; b' = s*a + c*b   (3 pk-FMA vs 4; R15-verified)
template<int BIT>
__device__ __forceinline__ void apply_ry16(f2 v[16], f2 ww, f2 ss) {
  #pragma unroll
  for (int j = 0; j < 16; ++j) {
    if (j & (1 << BIT)) continue;
    const int k = j | (1 << BIT);
    f2 a = v[j], b = v[k];
    a = pk_fma(b, ww, a);
    b = pk_fma(a, ss, b);
    a = pk_fma(b, ww, a);
    v[j] = a; v[k] = b;
  }
}

// ---------------------------------------------------------------------------
// Prep kernel — verbatim R15/R19 (verified).
// w layout: w[(l*NQ + q)*3 + c], c: 0=phi, 1=theta, 2=omega.
// ---------------------------------------------------------------------------
__global__ __launch_bounds__(256)
void qprep_kernel(const float* __restrict__ w, float* __restrict__ ws) {
  const int t = threadIdx.x;

  {
    float f = 0.f;
    #pragma unroll
    for (int k = 0; k < 8; ++k) {
      float p = w[(0*NQ + 7 - k)*3 + 0];
      f += ((t >> k) & 1) ? 0.5f*p : -0.5f*p;
    }
    float sv, cv; sincosf(f, &sv, &cv);
    ws[WS_WA0 + 2*t] = cv; ws[WS_WA0 + 2*t + 1] = sv;
  }

  #pragma unroll 1
  for (int l = 0; l < NL-1; ++l) {
    float f = 0.f;
    const int gt = t ^ (t >> 1);
    #pragma unroll
    for (int k = 0; k < 8; ++k) {
      float om = w[(l*NQ + 11 - k)*3 + 2];
      f += ((t >> k) & 1) ? 0.5f*om : -0.5f*om;
    }
    #pragma unroll
    for (int k = 0; k < 7; ++k) {
      float ph = w[((l+1)*NQ + 11 - k)*3 + 0];
      f += ((gt >> k) & 1) ? 0.5f*ph : -0.5f*ph;
    }
    float sv, cv; sincosf(f, &sv, &cv);
    ws[WS_W + (l*256 + t)*2] = cv; ws[WS_W + (l*256 + t)*2 + 1] = sv;
  }

  if (t < 16) {
    float f = 0.f;
    #pragma unroll
    for (int m = 0; m < 4; ++m) {
      float p = w[(0*NQ + 11 - m)*3 + 0];
      f += ((t >> m) & 1) ? 0.5f*p : -0.5f*p;
    }
    float sv, cv; sincosf(f, &sv, &cv);
    ws[WS_ZA0 + 2*t] = cv; ws[WS_ZA0 + 2*t + 1] = sv;
  }

  if (t < 160) {
    const int l = t >> 5, h = (t >> 4) & 1, j = t & 15;
    float f = 0.f;
    #pragma unroll
    for (int m = 0; m < 4; ++m) {
      float om = w[(l*NQ + 3 - m)*3 + 2];
      f += ((j >> m) & 1) ? 0.5f*om : -0.5f*om;
    }
    {
      float p4 = w[((l+1)*NQ + 4)*3 + 0];
      f += (h ^ (j & 1)) ? 0.5f*p4 : -0.5f*p4;
    }
    const int gj = j ^ (j >> 1);
    #pragma unroll
    for (int m = 0; m < 4; ++m) {
      float ph = w[((l+1)*NQ + 3 - m)*3 + 0];
      f += ((gj >> m) & 1) ? 0.5f*ph : -0.5f*ph;
    }
    float sv, cv; sincosf(f, &sv, &cv);
    ws[WS_ZM + 2*t] = cv; ws[WS_ZM + 2*t + 1] = sv;
  }

  // lifting coeffs of the half-angle rotation: s = sin(th/2), w = -tan(th/4)
  if (t < NL*NQ) {
    float th = w[t*3 + 1];
    float sv = sinf(0.5f*th);
    float wv = -tanf(0.25f*th);
    ((float4*)(ws + WS_RYT))[t] = make_float4(wv, wv, sv, sv);
  }
}

// ---------------------------------------------------------------------------
// Main kernel. LDS = 32768 B exactly -> 5 blocks/CU. (R19 body + setprio.)
// ---------------------------------------------------------------------------
__global__ __launch_bounds__(TPB, 5)
void qsim12_kernel(const float* __restrict__ x, const float* __restrict__ ws,
                   float* __restrict__ out) {
  __shared__ __align__(16) float st[2*DIM];   // 32 KB state (swizzled) ONLY

  const int t = threadIdx.x;
  const int b = blockIdx.x;
  char* stb = (char*)st;

  // x cos/sin: lanes 0-11 of each wave compute, readlane-broadcast to SGPRs.
  float csx[NQ], csy[NQ];
  {
    const int q = t & 63;
    float xv = (q < NQ) ? x[b*NQ + q] : 0.f;
    float sv, cv; sincosf(0.5f*xv, &sv, &cv);
    #pragma unroll
    for (int qq = 0; qq < NQ; ++qq) {
      csx[qq] = __int_as_float(__builtin_amdgcn_readlane(__float_as_int(cv), qq));
      csy[qq] = __int_as_float(__builtin_amdgcn_readlane(__float_as_int(sv), qq));
    }
  }

  // Precomputed byte-address bases (verified R5/R7 — unchanged).
  int baseA[8], baseB[8];
  #pragma unroll
  for (int m = 0; m < 8; ++m) {
    baseA[m] = (t << 7) + (((2*m) ^ (t & 14)) << 3);                 // phys14, A b128
    baseB[m] = ((t >> 4) << 11) + ((((t & 15) ^ (2*m))) << 3);       // + j*128
  }
  const int baseC = ((t >> 4) << 7) + ((((t & 15) ^ ((t >> 4) & 15))) << 3);  // + j*2048
  const int G = t ^ (t >> 1);
  int baseS[2];
  #pragma unroll
  for (int par = 0; par < 2; ++par) {
    const int k8 = par << 3;
    baseS[par] = ((((G >> 4) & 15) ^ k8) << 7)
               + ((((G & 15) ^ ((G >> 4) & 14) ^ k8)) << 3);
  }

  f2 v[16];

  // ---- Init: amp(label) = prod_w (bit? sin:cos) * (-i)^popcount(label).
  {
    float rhi = 1.f;
    #pragma unroll
    for (int k = 0; k < 8; ++k)
      rhi *= ((t >> k) & 1) ? csy[7-k] : csx[7-k];
    const int popt = __popc(t);
    #pragma unroll
    for (int j = 0; j < 16; ++j) {
      float r = rhi;
      #pragma unroll
      for (int m = 0; m < 4; ++m)
        r *= ((j >> m) & 1) ? csy[11-m] : csx[11-m];
      const int pj = (popt + __popc(j)) & 3;
      if      (pj == 0) v[j] = (f2){ r, 0.f};
      else if (pj == 1) v[j] = (f2){0.f, -r};
      else if (pj == 2) v[j] = (f2){-r, 0.f};
      else              v[j] = (f2){0.f,  r};
    }
  }

  #define RY(BIT, WQ)                                                     \
    { const float4 r = *(const float4*)(ws + WS_RYT + 4*(l*NQ + (WQ)));   \
      apply_ry16<BIT>(v, (f2){r.x, r.y}, (f2){r.z, r.w}); }
  #define PRIO_HI() __builtin_amdgcn_s_setprio(1)
  #define PRIO_LO() __builtin_amdgcn_s_setprio(0)

  #pragma unroll 1
  for (int l = 0; l < NL; ++l) {
    // ---- pass A: wires 11..8 (label bits 0..3)
    if (l > 0) {
      // diag for this boundary was already applied (merged) at pass C of l-1
      #pragma unroll
      for (int m = 0; m < 8; ++m) {
        float4 q4 = *(const float4*)(stb + baseA[m]);
        v[2*m]   = (f2){q4.x, q4.y};
        v[2*m+1] = (f2){q4.z, q4.w};
      }
    } else {
      // D_phi(0): group (label bits 0-3) table x thread factor
      const float2 wv = *(const float2*)(ws + WS_WA0 + 2*t);
      const f2 wA0 = (f2){wv.x, wv.y};
      #pragma unroll
      for (int j = 0; j < 16; ++j) {
        const float2 zv = *(const float2*)(ws + WS_ZA0 + 2*j);
        v[j] = cmulp(cmulp(v[j], (f2){zv.x, zv.y}), wA0);
      }
    }
    PRIO_HI();
    RY(0,11) RY(1,10) RY(2,9) RY(3,8)
    PRIO_LO();
    #pragma unroll
    for (int m = 0; m < 8; ++m)
      *(float4*)(stb + baseA[m]) =
          make_float4(v[2*m].x, v[2*m].y, v[2*m+1].x, v[2*m+1].y);
    __syncthreads();

    // ---- pass B: wires 7..4 (label bits 4..7); load phys14, store phys15
    #pragma unroll
    for (int m = 0; m < 8; ++m) {
      v[2*m]   = *(const f2*)(stb + baseB[m] + (2*m)*128);
      v[2*m+1] = *(const f2*)(stb + baseB[m] + (2*m+1)*128);
    }
    PRIO_HI();
    RY(0,7) RY(1,6) RY(2,5) RY(3,4)
    PRIO_LO();
    #pragma unroll
    for (int m = 0; m < 8; ++m) {
      *(f2*)(stb + baseB[m] + (2*m)*128)         = v[2*m];
      *(f2*)(stb + (baseB[m] ^ 8) + (2*m+1)*128) = v[2*m+1];
    }
    __syncthreads();

    // ---- pass C: wires 3..0 (label bits 8..11); load phys15
    #pragma unroll
    for (int j = 0; j < 16; ++j)
      v[j] = *(const f2*)(stb + baseC + j*2048);
    if (l < NL-1) {
      PRIO_HI();
      RY(0,3) RY(1,2) RY(2,1) RY(3,0)
      // merged diag: D_om(l) * D_phi(l+1) evaluated at post-CNOT label
      // gray(lambda). Group part zM[l][t7][j], thread part W[l][t].
      const float2 wv = *(const float2*)(ws + WS_W + (l*TPB + t)*2);
      const f2 W = (f2){wv.x, wv.y};
      const float* zmb = ws + WS_ZM + ((l*2 + ((t >> 7) & 1))*16)*2;
      #pragma unroll
      for (int j = 0; j < 16; ++j) {
        const float2 zv = *(const float2*)(zmb + 2*j);
        v[j] = cmulp(cmulp(v[j], (f2){zv.x, zv.y}), W);
      }
      PRIO_LO();
      // store with CNOT fold: slot = gray(label), layout phys14;
      // high nibble of gray(label) = gray4(j)
      #pragma unroll
      for (int j = 0; j < 16; ++j) {
        const int g4 = (j ^ (j >> 1)) & 15;
        *(f2*)(stb + baseS[j & 1] + (g4 << 11)) = v[j];
      }
      __syncthreads();
    } else {
      PRIO_HI();
      RY(0,3) RY(1,2) RY(2,1) RY(3,0)
      PRIO_LO();
    }
  }

  // ---- Epilogue: labels s = t | j<<8; post-CNOT wire0 = j3, wire1 = j2^j3.
  float a0 = 0.f, a1 = 0.f;
  #pragma unroll
  for (int j = 0; j < 16; ++j) {
    float pr = v[j].x*v[j].x + v[j].y*v[j].y;
    a0 += ((j >> 3) & 1) ? -pr : pr;
    a1 += (((j >> 2) ^ (j >> 3)) & 1) ? -pr : pr;
  }
  #pragma unroll
  for (int off = 32; off >= 1; off >>= 1) {
    a0 += __shfl_down(a0, off);
    a1 += __shfl_down(a1, off);
  }
  __syncthreads();                 // all LDS reads done before st reuse
  if ((t & 63) == 0) { st[(t >> 6)*2] = a0; st[(t >> 6)*2 + 1] = a1; }
  __syncthreads();
  if (t == 0) {
    out[b*2 + 0] = st[0] + st[2] + st[4] + st[6];
    out[b*2 + 1] = st[1] + st[3] + st[5] + st[7];
  }
}

extern "C" void kernel_launch(void* const* d_in, const int* in_sizes, int n_in,
                              void* d_out, int out_size, void* d_ws, size_t ws_size,
                              hipStream_t stream) {
  const float* x = (const float*)d_in[0];      // (B, 12) f32
  const float* w = (const float*)d_in[1];      // (6, 12, 3) f32
  float* out = (float*)d_out;                  // (B, 2) f32
  float* ws = (float*)d_ws;                    // needs >= 14848 B
  int B = in_sizes[0] / NQ;
  qprep_kernel<<<1, 256, 0, stream>>>(w, ws);
  qsim12_kernel<<<B, TPB, 0, stream>>>(x, ws, out);
}

// Round 16
// 124.382 us; speedup vs baseline: 1.0175x; 1.0157x over previous
//
#include <hip/hip_runtime.h>
#include <math.h>

#define NQ 12
#define DIM 4096
#define NL 6
#define TPB 256

// ---------------------------------------------------------------------------
// FINAL (R19/R15, verified 3x: passed, absmax 0.0039, bench 125us):
// R9 3-pass barrier-synced structure + merged boundary diagonals + lifting
// RY butterflies + workspace-precomputed tables + 32KB-exact LDS.
//
// Session ledger (what's IN and why):
//  - Diagonal merge: D_om(l) and D_phi(l+1) commute past the CNOT chain as
//    one diagonal applied at pass C, evaluated at post-CNOT gray(label)
//    (-16% VALU, R9).
//  - Lifting RY: R = [[1,w],[0,1]][[1,0],[s,1]][[1,w],[0,1]] with
//    s = sin(th/2), w = -tan(th/4); butterfly = 3 pk-FMA vs 4 (-21% VALU,
//    R15). Half-angle coeffs are essential (R14 erratum).
//  - Tables in d_ws via prep kernel; LDS = state only = 32768 B.
// What's OUT (tested, refuted):
//  - 1-wave / bpermute / 2-elem ILP structures (R10/11/16/17: latency-bound).
//  - Barrier weakening (R18: RACES despite wave-private address proof) and
//    token-sharing (R13). Persistent blocks (R20: null). setprio (R21: null).
//  - launch_bounds arg2>=2 (R11/12: caps VGPR at 128 -> catastrophic spill).
// Remaining gap to the ~35us VALU+LDS floor is intrinsic phase serialization
// of the barrier-synced 3-pass structure; all identified exits refuted.
// ---------------------------------------------------------------------------

// ---- d_ws table layout (float offsets) ----
#define WS_WA0 0      // 256 f2  : layer-0 D_phi thread factor e^{i fA0(t)}
#define WS_W   512    // 5*256 f2: merged D_om(l)*D_phi(l+1) thread factor
#define WS_ZA0 3072   // 16 f2   : layer-0 D_phi group factor (label bits 0-3)
#define WS_ZM  3104   // 5*2*16 f2: merged group factor, idx ((l*2+t7)*16+j)
#define WS_RYT 3424   // 72 float4: (w,w,s,s) per (l,wire)  [lifting coeffs]
#define WS_FLOATS 3712  // 14848 bytes total

typedef float f2 __attribute__((ext_vector_type(2)));

__device__ __forceinline__ f2 pk_mul(f2 a, f2 b) {
  f2 d; asm("v_pk_mul_f32 %0, %1, %2" : "=v"(d) : "v"(a), "v"(b)); return d;
}
__device__ __forceinline__ f2 pk_fma(f2 a, f2 b, f2 c) {
  f2 d; asm("v_pk_fma_f32 %0, %1, %2, %3" : "=v"(d) : "v"(a), "v"(b), "v"(c)); return d;
}
// complex mul, both operands packed (re,im)
__device__ __forceinline__ f2 cmulp(f2 a, f2 c) {
  f2 r1, d;
  asm("v_pk_mul_f32 %0, %1, %2 op_sel:[0,0] op_sel_hi:[0,1]"
      : "=v"(r1) : "v"(a), "v"(c));
  asm("v_pk_fma_f32 %0, %1, %2, %3 op_sel:[1,1,0] op_sel_hi:[1,0,1] neg_lo:[1,0,0]"
      : "=v"(d) : "v"(a), "v"(c), "v"(r1));
  return d;
}

// Lifting RY pair update: a += w*b; b += s*a; a += w*b
// == a' = c*a - s*b ; b' = s*a + c*b   (3 pk-FMA vs 4)
template<int BIT>
__device__ __forceinline__ void apply_ry16(f2 v[16], f2 ww, f2 ss) {
  #pragma unroll
  for (int j = 0; j < 16; ++j) {
    if (j & (1 << BIT)) continue;
    const int k = j | (1 << BIT);
    f2 a = v[j], b = v[k];
    a = pk_fma(b, ww, a);
    b = pk_fma(a, ss, b);
    a = pk_fma(b, ww, a);
    v[j] = a; v[k] = b;
  }
}

// ---------------------------------------------------------------------------
// Prep kernel: 1 block x 256 threads, fills d_ws from w. Runs once, ~2 us.
// w layout: w[(l*NQ + q)*3 + c], c: 0=phi, 1=theta, 2=omega.
// ---------------------------------------------------------------------------
__global__ __launch_bounds__(256)
void qprep_kernel(const float* __restrict__ w, float* __restrict__ ws) {
  const int t = threadIdx.x;

  // WA0[t] = e^{i * sum_k (t_k ? + : -) phi(0, 7-k)/2}   (label bit 4+k)
  {
    float f = 0.f;
    #pragma unroll
    for (int k = 0; k < 8; ++k) {
      float p = w[(0*NQ + 7 - k)*3 + 0];
      f += ((t >> k) & 1) ? 0.5f*p : -0.5f*p;
    }
    float sv, cv; sincosf(f, &sv, &cv);
    ws[WS_WA0 + 2*t] = cv; ws[WS_WA0 + 2*t + 1] = sv;
  }

  // W[l][t], l=0..4: omega(l) over t_k (label bit k <-> wire 11-k)
  //                + phi(l+1) over gray bits g_k = t_k^t_{k+1}, k=0..6
  #pragma unroll 1
  for (int l = 0; l < NL-1; ++l) {
    float f = 0.f;
    const int gt = t ^ (t >> 1);
    #pragma unroll
    for (int k = 0; k < 8; ++k) {
      float om = w[(l*NQ + 11 - k)*3 + 2];
      f += ((t >> k) & 1) ? 0.5f*om : -0.5f*om;
    }
    #pragma unroll
    for (int k = 0; k < 7; ++k) {
      float ph = w[((l+1)*NQ + 11 - k)*3 + 0];
      f += ((gt >> k) & 1) ? 0.5f*ph : -0.5f*ph;
    }
    float sv, cv; sincosf(f, &sv, &cv);
    ws[WS_W + (l*256 + t)*2] = cv; ws[WS_W + (l*256 + t)*2 + 1] = sv;
  }

  // zA0[j], j<16: phi(0) over j_m (label bit m <-> wire 11-m)
  if (t < 16) {
    float f = 0.f;
    #pragma unroll
    for (int m = 0; m < 4; ++m) {
      float p = w[(0*NQ + 11 - m)*3 + 0];
      f += ((t >> m) & 1) ? 0.5f*p : -0.5f*p;
    }
    float sv, cv; sincosf(f, &sv, &cv);
    ws[WS_ZA0 + 2*t] = cv; ws[WS_ZA0 + 2*t + 1] = sv;
  }

  // zM[l][h][j], idx = (l*2+h)*16+j, t<160:
  //   omega(l):  wires 3-m by j_m (label bits 8-11)
  //   phi(l+1):  g7 = h^j0 -> wire4; g8..g11 = (j^(j>>1)) bits 0..3 -> wires 3..0
  if (t < 160) {
    const int l = t >> 5, h = (t >> 4) & 1, j = t & 15;
    float f = 0.f;
    #pragma unroll
    for (int m = 0; m < 4; ++m) {
      float om = w[(l*NQ + 3 - m)*3 + 2];
      f += ((j >> m) & 1) ? 0.5f*om : -0.5f*om;
    }
    {
      float p4 = w[((l+1)*NQ + 4)*3 + 0];
      f += (h ^ (j & 1)) ? 0.5f*p4 : -0.5f*p4;
    }
    const int gj = j ^ (j >> 1);
    #pragma unroll
    for (int m = 0; m < 4; ++m) {
      float ph = w[((l+1)*NQ + 3 - m)*3 + 0];
      f += ((gj >> m) & 1) ? 0.5f*ph : -0.5f*ph;
    }
    float sv, cv; sincosf(f, &sv, &cv);
    ws[WS_ZM + 2*t] = cv; ws[WS_ZM + 2*t + 1] = sv;
  }

  // ryt[g], g<72: lifting coeffs of the HALF-ANGLE rotation:
  //   butterfly rotation angle is th/2  ->  s = sin(th/2), w = -tan(th/4)
  if (t < NL*NQ) {
    float th = w[t*3 + 1];
    float sv = sinf(0.5f*th);
    float wv = -tanf(0.25f*th);
    ((float4*)(ws + WS_RYT))[t] = make_float4(wv, wv, sv, sv);
  }
}

// ---------------------------------------------------------------------------
// Main kernel. LDS = 32768 B exactly -> 5 blocks/CU.
// ---------------------------------------------------------------------------
__global__ __launch_bounds__(TPB, 5)
void qsim12_kernel(const float* __restrict__ x, const float* __restrict__ ws,
                   float* __restrict__ out) {
  __shared__ __align__(16) float st[2*DIM];   // 32 KB state (swizzled) ONLY

  const int t = threadIdx.x;
  const int b = blockIdx.x;
  char* stb = (char*)st;

  // x cos/sin: lanes 0-11 of each wave compute, readlane-broadcast to SGPRs.
  float csx[NQ], csy[NQ];
  {
    const int q = t & 63;
    float xv = (q < NQ) ? x[b*NQ + q] : 0.f;
    float sv, cv; sincosf(0.5f*xv, &sv, &cv);
    #pragma unroll
    for (int qq = 0; qq < NQ; ++qq) {
      csx[qq] = __int_as_float(__builtin_amdgcn_readlane(__float_as_int(cv), qq));
      csy[qq] = __int_as_float(__builtin_amdgcn_readlane(__float_as_int(sv), qq));
    }
  }

  // Precomputed byte-address bases (verified R5/R7 — unchanged).
  int baseA[8], baseB[8];
  #pragma unroll
  for (int m = 0; m < 8; ++m) {
    baseA[m] = (t << 7) + (((2*m) ^ (t & 14)) << 3);                 // phys14, A b128
    baseB[m] = ((t >> 4) << 11) + ((((t & 15) ^ (2*m))) << 3);       // + j*128
  }
  const int baseC = ((t >> 4) << 7) + ((((t & 15) ^ ((t >> 4) & 15))) << 3);  // + j*2048
  const int G = t ^ (t >> 1);
  int baseS[2];
  #pragma unroll
  for (int par = 0; par < 2; ++par) {
    const int k8 = par << 3;
    baseS[par] = ((((G >> 4) & 15) ^ k8) << 7)
               + ((((G & 15) ^ ((G >> 4) & 14) ^ k8)) << 3);
  }

  f2 v[16];

  // ---- Init: amp(label) = prod_w (bit? sin:cos) * (-i)^popcount(label).
  {
    float rhi = 1.f;
    #pragma unroll
    for (int k = 0; k < 8; ++k)
      rhi *= ((t >> k) & 1) ? csy[7-k] : csx[7-k];
    const int popt = __popc(t);
    #pragma unroll
    for (int j = 0; j < 16; ++j) {
      float r = rhi;
      #pragma unroll
      for (int m = 0; m < 4; ++m)
        r *= ((j >> m) & 1) ? csy[11-m] : csx[11-m];
      const int pj = (popt + __popc(j)) & 3;
      if      (pj == 0) v[j] = (f2){ r, 0.f};
      else if (pj == 1) v[j] = (f2){0.f, -r};
      else if (pj == 2) v[j] = (f2){-r, 0.f};
      else              v[j] = (f2){0.f,  r};
    }
  }

  #define RY(BIT, WQ)                                                     \
    { const float4 r = *(const float4*)(ws + WS_RYT + 4*(l*NQ + (WQ)));   \
      apply_ry16<BIT>(v, (f2){r.x, r.y}, (f2){r.z, r.w}); }

  #pragma unroll 1
  for (int l = 0; l < NL; ++l) {
    // ---- pass A: wires 11..8 (label bits 0..3)
    if (l > 0) {
      // diag for this boundary was already applied (merged) at pass C of l-1
      #pragma unroll
      for (int m = 0; m < 8; ++m) {
        float4 q4 = *(const float4*)(stb + baseA[m]);
        v[2*m]   = (f2){q4.x, q4.y};
        v[2*m+1] = (f2){q4.z, q4.w};
      }
    } else {
      // D_phi(0): group (label bits 0-3) table x thread factor
      const float2 wv = *(const float2*)(ws + WS_WA0 + 2*t);
      const f2 wA0 = (f2){wv.x, wv.y};
      #pragma unroll
      for (int j = 0; j < 16; ++j) {
        const float2 zv = *(const float2*)(ws + WS_ZA0 + 2*j);
        v[j] = cmulp(cmulp(v[j], (f2){zv.x, zv.y}), wA0);
      }
    }
    RY(0,11) RY(1,10) RY(2,9) RY(3,8)
    #pragma unroll
    for (int m = 0; m < 8; ++m)
      *(float4*)(stb + baseA[m]) =
          make_float4(v[2*m].x, v[2*m].y, v[2*m+1].x, v[2*m+1].y);
    __syncthreads();

    // ---- pass B: wires 7..4 (label bits 4..7); load phys14, store phys15
    #pragma unroll
    for (int m = 0; m < 8; ++m) {
      v[2*m]   = *(const f2*)(stb + baseB[m] + (2*m)*128);
      v[2*m+1] = *(const f2*)(stb + baseB[m] + (2*m+1)*128);
    }
    RY(0,7) RY(1,6) RY(2,5) RY(3,4)
    #pragma unroll
    for (int m = 0; m < 8; ++m) {
      *(f2*)(stb + baseB[m] + (2*m)*128)         = v[2*m];
      *(f2*)(stb + (baseB[m] ^ 8) + (2*m+1)*128) = v[2*m+1];
    }
    __syncthreads();

    // ---- pass C: wires 3..0 (label bits 8..11); load phys15
    #pragma unroll
    for (int j = 0; j < 16; ++j)
      v[j] = *(const f2*)(stb + baseC + j*2048);
    RY(0,3) RY(1,2) RY(2,1) RY(3,0)
    if (l < NL-1) {
      // merged diag: D_om(l) * D_phi(l+1) evaluated at post-CNOT label
      // gray(lambda). Group part zM[l][t7][j], thread part W[l][t].
      const float2 wv = *(const float2*)(ws + WS_W + (l*TPB + t)*2);
      const f2 W = (f2){wv.x, wv.y};
      const float* zmb = ws + WS_ZM + ((l*2 + ((t >> 7) & 1))*16)*2;
      #pragma unroll
      for (int j = 0; j < 16; ++j) {
        const float2 zv = *(const float2*)(zmb + 2*j);
        v[j] = cmulp(cmulp(v[j], (f2){zv.x, zv.y}), W);
      }
      // store with CNOT fold: slot = gray(label), layout phys14;
      // high nibble of gray(label) = gray4(j)
      #pragma unroll
      for (int j = 0; j < 16; ++j) {
        const int g4 = (j ^ (j >> 1)) & 15;
        *(f2*)(stb + baseS[j & 1] + (g4 << 11)) = v[j];
      }
      __syncthreads();
    }
  }

  // ---- Epilogue: labels s = t | j<<8; post-CNOT wire0 = j3, wire1 = j2^j3.
  float a0 = 0.f, a1 = 0.f;
  #pragma unroll
  for (int j = 0; j < 16; ++j) {
    float pr = v[j].x*v[j].x + v[j].y*v[j].y;
    a0 += ((j >> 3) & 1) ? -pr : pr;
    a1 += (((j >> 2) ^ (j >> 3)) & 1) ? -pr : pr;
  }
  #pragma unroll
  for (int off = 32; off >= 1; off >>= 1) {
    a0 += __shfl_down(a0, off);
    a1 += __shfl_down(a1, off);
  }
  __syncthreads();                 // all LDS reads done before st reuse
  if ((t & 63) == 0) { st[(t >> 6)*2] = a0; st[(t >> 6)*2 + 1] = a1; }
  __syncthreads();
  if (t == 0) {
    out[b*2 + 0] = st[0] + st[2] + st[4] + st[6];
    out[b*2 + 1] = st[1] + st[3] + st[5] + st[7];
  }
}

extern "C" void kernel_launch(void* const* d_in, const int* in_sizes, int n_in,
                              void* d_out, int out_size, void* d_ws, size_t ws_size,
                              hipStream_t stream) {
  const float* x = (const float*)d_in[0];      // (B, 12) f32
  const float* w = (const float*)d_in[1];      // (6, 12, 3) f32
  float* out = (float*)d_out;                  // (B, 2) f32
  float* ws = (float*)d_ws;                    // needs >= 14848 B
  int B = in_sizes[0] / NQ;
  qprep_kernel<<<1, 256, 0, stream>>>(w, ws);
  qsim12_kernel<<<B, TPB, 0, stream>>>(x, ws, out);
}